// Round 1
// baseline (250.905 us; speedup 1.0000x reference)
//
#include <hip/hip_runtime.h>
#include <math.h>

// Problem constants
#define NN 8
#define C_TOTAL 448
#define CC 100
#define HH 56
#define WW 56
#define HW (HH*WW)          // 3136
#define OH 224
#define OW 224
#define CT 10               // c-chunk size (registers)
#define DT 4                // d-tile size (registers)
#define NCHUNK (CC/CT)      // 10
#define NTILE (HW/64)       // 49 pixel tiles

// ---------------------------------------------------------------------------
// Kernel A: per-pixel quadratic form, partial over c-chunk.
// Block = 512 threads = 8 waves; wave w handles image n=w, lane = pixel in tile.
// grid.x = NTILE * NCHUNK.
// qpart[chunk][n][pix] = sum_{c in chunk} sum_d x[n,c,pix]*cov[c,d,pix]*x[n,d,pix]
// ---------------------------------------------------------------------------
__global__ __launch_bounds__(512) void qform_kernel(
    const float* __restrict__ fmaps, const int* __restrict__ sel,
    const float* __restrict__ mean, const float* __restrict__ cov,
    float* __restrict__ qpart)
{
    const int tile  = blockIdx.x % NTILE;
    const int chunk = blockIdx.x / NTILE;     // 0..NCHUNK-1
    const int n     = threadIdx.x >> 6;       // 0..7 (wave id)
    const int pix   = tile * 64 + (threadIdx.x & 63);
    const int c0    = chunk * CT;

    __shared__ int s_sel[CC];
    if (threadIdx.x < CC) s_sel[threadIdx.x] = sel[threadIdx.x];
    __syncthreads();

    const float* fm_n = fmaps + (size_t)n * C_TOTAL * HW;

    // preload xc[CT] = gathered, mean-subtracted values for this chunk's rows
    float xc[CT];
#pragma unroll
    for (int i = 0; i < CT; ++i) {
        const int c = c0 + i;
        xc[i] = fm_n[(size_t)s_sel[c] * HW + pix] - mean[(size_t)c * HW + pix];
    }

    float acc = 0.0f;
    for (int d0 = 0; d0 < CC; d0 += DT) {
        float xd[DT];
#pragma unroll
        for (int j = 0; j < DT; ++j) {
            const int d = d0 + j;
            xd[j] = fm_n[(size_t)s_sel[d] * HW + pix] - mean[(size_t)d * HW + pix];
        }
#pragma unroll
        for (int i = 0; i < CT; ++i) {
            const float* cp = cov + ((size_t)(c0 + i) * CC + d0) * HW + pix;
#pragma unroll
            for (int j = 0; j < DT; ++j) {
                acc = fmaf(xc[i] * xd[j], cp[(size_t)j * HW], acc);
            }
        }
    }
    qpart[((size_t)chunk * NN + n) * HW + pix] = acc;
}

// ---------------------------------------------------------------------------
// Kernel B: reduce partials over chunks, sqrt -> s_map (N,HW)
// ---------------------------------------------------------------------------
__global__ __launch_bounds__(256) void reduce_kernel(
    const float* __restrict__ qpart, float* __restrict__ smap)
{
    const int idx = blockIdx.x * 256 + threadIdx.x;
    if (idx >= NN * HW) return;
    float s = 0.0f;
#pragma unroll
    for (int k = 0; k < NCHUNK; ++k)
        s += qpart[(size_t)k * NN * HW + idx];
    smap[idx] = sqrtf(fmaxf(s, 0.0f));
}

// ---------------------------------------------------------------------------
// Kernel C: bilinear x4 upsample (half-pixel, edge clamp) + normalize
// ---------------------------------------------------------------------------
__global__ __launch_bounds__(256) void upsample_kernel(
    const float* __restrict__ smap,
    const float* __restrict__ minp, const float* __restrict__ maxp,
    float* __restrict__ out)
{
    const int idx = blockIdx.x * 256 + threadIdx.x;
    const int total = NN * OH * OW;
    if (idx >= total) return;

    const int ox = idx % OW;
    const int oy = (idx / OW) % OH;
    const int n  = idx / (OW * OH);

    const float fy = oy * 0.25f - 0.375f;
    const float fx = ox * 0.25f - 0.375f;

    int y0 = (int)floorf(fy);
    int x0 = (int)floorf(fx);
    const float wy = fy - (float)y0;
    const float wx = fx - (float)x0;
    int y1 = min(y0 + 1, HH - 1); y0 = max(y0, 0);
    int x1 = min(x0 + 1, WW - 1); x0 = max(x0, 0);

    const float* s = smap + (size_t)n * HW;
    const float v00 = s[y0 * WW + x0];
    const float v01 = s[y0 * WW + x1];
    const float v10 = s[y1 * WW + x0];
    const float v11 = s[y1 * WW + x1];

    const float v = (1.0f - wy) * ((1.0f - wx) * v00 + wx * v01)
                  +          wy * ((1.0f - wx) * v10 + wx * v11);

    const float mn = *minp;
    const float mx = *maxp;
    out[idx] = (v - mn) / (mx - mn);
}

// ---------------------------------------------------------------------------
extern "C" void kernel_launch(void* const* d_in, const int* in_sizes, int n_in,
                              void* d_out, int out_size, void* d_ws, size_t ws_size,
                              hipStream_t stream)
{
    const float* fmaps = (const float*)d_in[0];
    const int*   sel   = (const int*)  d_in[1];
    const float* mean  = (const float*)d_in[2];
    const float* cov   = (const float*)d_in[3];
    const float* minp  = (const float*)d_in[4];
    const float* maxp  = (const float*)d_in[5];
    float* out = (float*)d_out;

    float* qpart = (float*)d_ws;                       // NCHUNK*NN*HW floats
    float* smap  = qpart + (size_t)NCHUNK * NN * HW;   // NN*HW floats

    qform_kernel<<<NTILE * NCHUNK, 512, 0, stream>>>(fmaps, sel, mean, cov, qpart);
    reduce_kernel<<<(NN * HW + 255) / 256, 256, 0, stream>>>(qpart, smap);

    const int total = NN * OH * OW;
    upsample_kernel<<<(total + 255) / 256, 256, 0, stream>>>(smap, minp, maxp, out);
}

// Round 2
// 247.450 us; speedup vs baseline: 1.0140x; 1.0140x over previous
//
#include <hip/hip_runtime.h>
#include <math.h>

// Problem constants
#define NN 8
#define C_TOTAL 448
#define CC 100
#define HH 56
#define WW 56
#define HW (HH*WW)          // 3136
#define NPIX4 (HW/4)        // 784 float4 columns
#define OH 224
#define OW 224
#define NPAIR 50            // row pairs (r, 99-r)
#define NT4 13              // ceil(784 / 64) pixel-quad tiles per wave

// float4 helpers (explicit, avoid relying on operator overloads)
__device__ __forceinline__ void fma4(float4& acc, const float4 a, const float4 b) {
    acc.x = fmaf(a.x, b.x, acc.x);
    acc.y = fmaf(a.y, b.y, acc.y);
    acc.z = fmaf(a.z, b.z, acc.z);
    acc.w = fmaf(a.w, b.w, acc.w);
}

// ---------------------------------------------------------------------------
// Kernel 0: x[n,c,pix] = fmaps[n, sel[c], pix] - mean[c, pix]   (float4 wide)
// ---------------------------------------------------------------------------
__global__ __launch_bounds__(256) void prep_x_kernel(
    const float* __restrict__ fmaps, const int* __restrict__ sel,
    const float* __restrict__ mean, float* __restrict__ xbuf)
{
    const int idx = blockIdx.x * 256 + threadIdx.x;
    const int total = NN * CC * NPIX4;
    if (idx >= total) return;
    const int p4 = idx % NPIX4;
    const int c  = (idx / NPIX4) % CC;
    const int n  = idx / (NPIX4 * CC);

    const float4* f4 = (const float4*)fmaps;
    const float4* m4 = (const float4*)mean;
    float4*       x4 = (float4*)xbuf;

    const float4 f = f4[((size_t)n * C_TOTAL + sel[c]) * NPIX4 + p4];
    const float4 m = m4[(size_t)c * NPIX4 + p4];
    float4 r;
    r.x = f.x - m.x; r.y = f.y - m.y; r.z = f.z - m.z; r.w = f.w - m.w;
    x4[((size_t)n * CC + c) * NPIX4 + p4] = r;
}

// ---------------------------------------------------------------------------
// Kernel 1: symmetric quadratic form, one row-pair (r, 99-r) per block.
// Block = 512 threads = 8 waves (wave = image n); lane owns 4 pixels (float4).
// qpart[r][n][pix] = 2*( x_r * (0.5*x_r*cov[r,r] + sum_{d>r} x_d cov[r,d])
//                      + x_s * (0.5*x_s*cov[s,s] + sum_{d>s} x_d cov[s,d]) )
// with s = 99-r.  Sum over r of qpart == full quadratic form (cov symmetric).
// ---------------------------------------------------------------------------
__global__ __launch_bounds__(512) void qform_kernel(
    const float* __restrict__ xbuf, const float* __restrict__ cov,
    float* __restrict__ qpart)
{
    const int tile = blockIdx.x % NT4;
    const int r    = blockIdx.x / NT4;      // 0..49
    const int s    = 99 - r;                // 50..99
    const int n    = threadIdx.x >> 6;
    const int p4   = tile * 64 + (threadIdx.x & 63);
    if (p4 >= NPIX4) return;

    const float4* x4  = (const float4*)xbuf + (size_t)n * CC * NPIX4;
    const float4* c4  = (const float4*)cov;

    // row base pointers at column d, advanced by NPIX4 each step
    const float4* covr = c4 + ((size_t)r * CC + r) * NPIX4 + p4;   // cov[r, d=r..]
    const float4* covs = c4 + ((size_t)s * CC + s) * NPIX4 + p4;   // cov[s, d=s..]
    const float4* xp   = x4 + (size_t)r * NPIX4 + p4;              // x[d=r..]

    float4 ir = make_float4(0.f, 0.f, 0.f, 0.f);
    float4 is = make_float4(0.f, 0.f, 0.f, 0.f);

    // d == r : half-weight diagonal for row r
    float4 xr = *xp;
    {
        float4 h; h.x = 0.5f*xr.x; h.y = 0.5f*xr.y; h.z = 0.5f*xr.z; h.w = 0.5f*xr.w;
        fma4(ir, h, *covr);
    }
    xp += NPIX4; covr += NPIX4;

    // r < d < s : row r only
#pragma unroll 4
    for (int d = r + 1; d < s; ++d) {
        const float4 xd = *xp;
        fma4(ir, xd, *covr);
        xp += NPIX4; covr += NPIX4;
    }

    // d == s : row r normal, row s half-weight diagonal
    float4 xs = *xp;
    fma4(ir, xs, *covr);
    {
        float4 h; h.x = 0.5f*xs.x; h.y = 0.5f*xs.y; h.z = 0.5f*xs.z; h.w = 0.5f*xs.w;
        fma4(is, h, *covs);
    }
    xp += NPIX4; covr += NPIX4; covs += NPIX4;

    // d > s : both rows share xd
#pragma unroll 4
    for (int d = s + 1; d < CC; ++d) {
        const float4 xd = *xp;
        fma4(ir, xd, *covr);
        fma4(is, xd, *covs);
        xp += NPIX4; covr += NPIX4; covs += NPIX4;
    }

    float4 q;
    q.x = 2.0f * (fmaf(xr.x, ir.x, xs.x * is.x));
    q.y = 2.0f * (fmaf(xr.y, ir.y, xs.y * is.y));
    q.z = 2.0f * (fmaf(xr.z, ir.z, xs.z * is.z));
    q.w = 2.0f * (fmaf(xr.w, ir.w, xs.w * is.w));

    float4* qp = (float4*)qpart;
    qp[((size_t)r * NN + n) * NPIX4 + p4] = q;
}

// ---------------------------------------------------------------------------
// Kernel 2: reduce partials over the 50 pairs, sqrt -> s_map (N,HW)
// ---------------------------------------------------------------------------
__global__ __launch_bounds__(256) void reduce_kernel(
    const float* __restrict__ qpart, float* __restrict__ smap)
{
    const int idx = blockIdx.x * 256 + threadIdx.x;   // over N*NPIX4
    if (idx >= NN * NPIX4) return;
    const int p4 = idx % NPIX4;
    const int n  = idx / NPIX4;

    const float4* qp = (const float4*)qpart;
    float4 acc = make_float4(0.f, 0.f, 0.f, 0.f);
#pragma unroll
    for (int k = 0; k < NPAIR; ++k) {
        const float4 v = qp[((size_t)k * NN + n) * NPIX4 + p4];
        acc.x += v.x; acc.y += v.y; acc.z += v.z; acc.w += v.w;
    }
    float4 o;
    o.x = sqrtf(fmaxf(acc.x, 0.f));
    o.y = sqrtf(fmaxf(acc.y, 0.f));
    o.z = sqrtf(fmaxf(acc.z, 0.f));
    o.w = sqrtf(fmaxf(acc.w, 0.f));
    ((float4*)smap)[(size_t)n * NPIX4 + p4] = o;
}

// ---------------------------------------------------------------------------
// Kernel 3: bilinear x4 upsample (half-pixel, edge clamp) + normalize
// ---------------------------------------------------------------------------
__global__ __launch_bounds__(256) void upsample_kernel(
    const float* __restrict__ smap,
    const float* __restrict__ minp, const float* __restrict__ maxp,
    float* __restrict__ out)
{
    const int idx = blockIdx.x * 256 + threadIdx.x;
    const int total = NN * OH * OW;
    if (idx >= total) return;

    const int ox = idx % OW;
    const int oy = (idx / OW) % OH;
    const int n  = idx / (OW * OH);

    const float fy = oy * 0.25f - 0.375f;
    const float fx = ox * 0.25f - 0.375f;

    int y0 = (int)floorf(fy);
    int x0 = (int)floorf(fx);
    const float wy = fy - (float)y0;
    const float wx = fx - (float)x0;
    int y1 = min(y0 + 1, HH - 1); y0 = max(y0, 0);
    int x1 = min(x0 + 1, WW - 1); x0 = max(x0, 0);

    const float* s = smap + (size_t)n * HW;
    const float v00 = s[y0 * WW + x0];
    const float v01 = s[y0 * WW + x1];
    const float v10 = s[y1 * WW + x0];
    const float v11 = s[y1 * WW + x1];

    const float v = (1.0f - wy) * ((1.0f - wx) * v00 + wx * v01)
                  +          wy * ((1.0f - wx) * v10 + wx * v11);

    const float mn = *minp;
    const float mx = *maxp;
    out[idx] = (v - mn) / (mx - mn);
}

// ---------------------------------------------------------------------------
extern "C" void kernel_launch(void* const* d_in, const int* in_sizes, int n_in,
                              void* d_out, int out_size, void* d_ws, size_t ws_size,
                              hipStream_t stream)
{
    const float* fmaps = (const float*)d_in[0];
    const int*   sel   = (const int*)  d_in[1];
    const float* mean  = (const float*)d_in[2];
    const float* cov   = (const float*)d_in[3];
    const float* minp  = (const float*)d_in[4];
    const float* maxp  = (const float*)d_in[5];
    float* out = (float*)d_out;

    float* xbuf  = (float*)d_ws;                          // NN*CC*HW      (10.0 MB)
    float* qpart = xbuf + (size_t)NN * CC * HW;           // NPAIR*NN*HW   ( 5.0 MB)
    float* smap  = qpart + (size_t)NPAIR * NN * HW;       // NN*HW         ( 0.1 MB)

    {
        const int total = NN * CC * NPIX4;
        prep_x_kernel<<<(total + 255) / 256, 256, 0, stream>>>(fmaps, sel, mean, xbuf);
    }
    qform_kernel<<<NT4 * NPAIR, 512, 0, stream>>>(xbuf, cov, qpart);
    {
        const int total = NN * NPIX4;
        reduce_kernel<<<(total + 255) / 256, 256, 0, stream>>>(qpart, smap);
    }
    {
        const int total = NN * OH * OW;
        upsample_kernel<<<(total + 255) / 256, 256, 0, stream>>>(smap, minp, maxp, out);
    }
}

// Round 3
// 235.468 us; speedup vs baseline: 1.0656x; 1.0509x over previous
//
#include <hip/hip_runtime.h>
#include <math.h>

// Problem constants
#define NN 8
#define C_TOTAL 448
#define CC 100
#define HH 56
#define WW 56
#define HW (HH*WW)          // 3136
#define NPIX4 (HW/4)        // 784 float4 / half4 columns
#define OH 224
#define OW 224
#define NPAIR 50            // row pairs (r, 99-r)
#define NT4 13              // ceil(784 / 64) pixel-quad tiles per wave

typedef __attribute__((ext_vector_type(4))) _Float16 half4;

__device__ __forceinline__ void fma4(float4& acc, const float4 a, const float4 b) {
    acc.x = fmaf(a.x, b.x, acc.x);
    acc.y = fmaf(a.y, b.y, acc.y);
    acc.z = fmaf(a.z, b.z, acc.z);
    acc.w = fmaf(a.w, b.w, acc.w);
}
__device__ __forceinline__ float4 h2f(const half4 h) {
    float4 r; r.x = (float)h.x; r.y = (float)h.y; r.z = (float)h.z; r.w = (float)h.w;
    return r;
}

// ---------------------------------------------------------------------------
// Kernel 0: x[n,c,pix] = fmaps[n, sel[c], pix] - mean[c, pix]  -> fp16 (half4)
// ---------------------------------------------------------------------------
__global__ __launch_bounds__(256) void prep_x_kernel(
    const float* __restrict__ fmaps, const int* __restrict__ sel,
    const float* __restrict__ mean, half4* __restrict__ xbuf)
{
    const int idx = blockIdx.x * 256 + threadIdx.x;
    const int total = NN * CC * NPIX4;
    if (idx >= total) return;
    const int p4 = idx % NPIX4;
    const int c  = (idx / NPIX4) % CC;
    const int n  = idx / (NPIX4 * CC);

    const float4* f4 = (const float4*)fmaps;
    const float4* m4 = (const float4*)mean;

    const float4 f = f4[((size_t)n * C_TOTAL + sel[c]) * NPIX4 + p4];
    const float4 m = m4[(size_t)c * NPIX4 + p4];
    half4 r;
    r.x = (_Float16)(f.x - m.x);
    r.y = (_Float16)(f.y - m.y);
    r.z = (_Float16)(f.z - m.z);
    r.w = (_Float16)(f.w - m.w);
    xbuf[((size_t)n * CC + c) * NPIX4 + p4] = r;
}

// ---------------------------------------------------------------------------
// Kernel 1: symmetric quadratic form, one row-pair (r, 99-r) per block.
// Block = 512 threads = 8 waves (wave = image n); lane owns 4 pixels.
// qpart[r][n][pix] = 2*( x_r*(0.5*x_r*cov[r,r] + sum_{d>r} x_d cov[r,d])
//                      + x_s*(0.5*x_s*cov[s,s] + sum_{d>s} x_d cov[s,d]) ), s=99-r
// ---------------------------------------------------------------------------
__global__ __launch_bounds__(512) void qform_kernel(
    const half4* __restrict__ xbuf, const float* __restrict__ cov,
    float* __restrict__ qpart)
{
    const int tile = blockIdx.x % NT4;
    const int r    = blockIdx.x / NT4;      // 0..49
    const int s    = 99 - r;                // 50..99
    const int n    = threadIdx.x >> 6;
    const int p4   = tile * 64 + (threadIdx.x & 63);
    if (p4 >= NPIX4) return;

    const half4*  x4 = xbuf + (size_t)n * CC * NPIX4;
    const float4* c4 = (const float4*)cov;

    const float4* covr = c4 + ((size_t)r * CC + r) * NPIX4 + p4;   // cov[r, d=r..]
    const float4* covs = c4 + ((size_t)s * CC + s) * NPIX4 + p4;   // cov[s, d=s..]
    const half4*  xp   = x4 + (size_t)r * NPIX4 + p4;              // x[d=r..]

    float4 ir = make_float4(0.f, 0.f, 0.f, 0.f);
    float4 is = make_float4(0.f, 0.f, 0.f, 0.f);

    // d == r : half-weight diagonal for row r
    const float4 xr = h2f(*xp);
    {
        float4 h; h.x = 0.5f*xr.x; h.y = 0.5f*xr.y; h.z = 0.5f*xr.z; h.w = 0.5f*xr.w;
        fma4(ir, h, *covr);
    }
    xp += NPIX4; covr += NPIX4;

    // r < d < s : row r only, unroll 4 with grouped loads
    int d = r + 1;
    for (; d + 3 < s; d += 4) {
        const half4  h0 = xp[0], h1 = xp[NPIX4], h2 = xp[2*NPIX4], h3 = xp[3*NPIX4];
        const float4 g0 = covr[0], g1 = covr[NPIX4], g2 = covr[2*NPIX4], g3 = covr[3*NPIX4];
        fma4(ir, h2f(h0), g0);
        fma4(ir, h2f(h1), g1);
        fma4(ir, h2f(h2), g2);
        fma4(ir, h2f(h3), g3);
        xp += 4*NPIX4; covr += 4*NPIX4;
    }
    for (; d < s; ++d) {
        fma4(ir, h2f(*xp), *covr);
        xp += NPIX4; covr += NPIX4;
    }

    // d == s : row r normal, row s half-weight diagonal
    const float4 xs = h2f(*xp);
    fma4(ir, xs, *covr);
    {
        float4 h; h.x = 0.5f*xs.x; h.y = 0.5f*xs.y; h.z = 0.5f*xs.z; h.w = 0.5f*xs.w;
        fma4(is, h, *covs);
    }
    xp += NPIX4; covr += NPIX4; covs += NPIX4;

    // d > s : both rows share xd, unroll 4 with grouped loads
    d = s + 1;
    for (; d + 3 < CC; d += 4) {
        const half4  h0 = xp[0], h1 = xp[NPIX4], h2 = xp[2*NPIX4], h3 = xp[3*NPIX4];
        const float4 a0 = covr[0], a1 = covr[NPIX4], a2 = covr[2*NPIX4], a3 = covr[3*NPIX4];
        const float4 b0 = covs[0], b1 = covs[NPIX4], b2 = covs[2*NPIX4], b3 = covs[3*NPIX4];
        const float4 f0 = h2f(h0), f1 = h2f(h1), f2 = h2f(h2), f3 = h2f(h3);
        fma4(ir, f0, a0); fma4(is, f0, b0);
        fma4(ir, f1, a1); fma4(is, f1, b1);
        fma4(ir, f2, a2); fma4(is, f2, b2);
        fma4(ir, f3, a3); fma4(is, f3, b3);
        xp += 4*NPIX4; covr += 4*NPIX4; covs += 4*NPIX4;
    }
    for (; d < CC; ++d) {
        const float4 f0 = h2f(*xp);
        fma4(ir, f0, *covr);
        fma4(is, f0, *covs);
        xp += NPIX4; covr += NPIX4; covs += NPIX4;
    }

    float4 q;
    q.x = 2.0f * (fmaf(xr.x, ir.x, xs.x * is.x));
    q.y = 2.0f * (fmaf(xr.y, ir.y, xs.y * is.y));
    q.z = 2.0f * (fmaf(xr.z, ir.z, xs.z * is.z));
    q.w = 2.0f * (fmaf(xr.w, ir.w, xs.w * is.w));

    float4* qp = (float4*)qpart;
    qp[((size_t)r * NN + n) * NPIX4 + p4] = q;
}

// ---------------------------------------------------------------------------
// Kernel 2: reduce partials over the 50 pairs, sqrt -> s_map (N,HW)
// ---------------------------------------------------------------------------
__global__ __launch_bounds__(256) void reduce_kernel(
    const float* __restrict__ qpart, float* __restrict__ smap)
{
    const int idx = blockIdx.x * 256 + threadIdx.x;   // over N*NPIX4
    if (idx >= NN * NPIX4) return;
    const int p4 = idx % NPIX4;
    const int n  = idx / NPIX4;

    const float4* qp = (const float4*)qpart;
    float4 acc = make_float4(0.f, 0.f, 0.f, 0.f);
#pragma unroll
    for (int k = 0; k < NPAIR; ++k) {
        const float4 v = qp[((size_t)k * NN + n) * NPIX4 + p4];
        acc.x += v.x; acc.y += v.y; acc.z += v.z; acc.w += v.w;
    }
    float4 o;
    o.x = sqrtf(fmaxf(acc.x, 0.f));
    o.y = sqrtf(fmaxf(acc.y, 0.f));
    o.z = sqrtf(fmaxf(acc.z, 0.f));
    o.w = sqrtf(fmaxf(acc.w, 0.f));
    ((float4*)smap)[(size_t)n * NPIX4 + p4] = o;
}

// ---------------------------------------------------------------------------
// Kernel 3: bilinear x4 upsample (half-pixel, edge clamp) + normalize
// ---------------------------------------------------------------------------
__global__ __launch_bounds__(256) void upsample_kernel(
    const float* __restrict__ smap,
    const float* __restrict__ minp, const float* __restrict__ maxp,
    float* __restrict__ out)
{
    const int idx = blockIdx.x * 256 + threadIdx.x;
    const int total = NN * OH * OW;
    if (idx >= total) return;

    const int ox = idx % OW;
    const int oy = (idx / OW) % OH;
    const int n  = idx / (OW * OH);

    const float fy = oy * 0.25f - 0.375f;
    const float fx = ox * 0.25f - 0.375f;

    int y0 = (int)floorf(fy);
    int x0 = (int)floorf(fx);
    const float wy = fy - (float)y0;
    const float wx = fx - (float)x0;
    int y1 = min(y0 + 1, HH - 1); y0 = max(y0, 0);
    int x1 = min(x0 + 1, WW - 1); x0 = max(x0, 0);

    const float* s = smap + (size_t)n * HW;
    const float v00 = s[y0 * WW + x0];
    const float v01 = s[y0 * WW + x1];
    const float v10 = s[y1 * WW + x0];
    const float v11 = s[y1 * WW + x1];

    const float v = (1.0f - wy) * ((1.0f - wx) * v00 + wx * v01)
                  +          wy * ((1.0f - wx) * v10 + wx * v11);

    const float mn = *minp;
    const float mx = *maxp;
    out[idx] = (v - mn) / (mx - mn);
}

// ---------------------------------------------------------------------------
extern "C" void kernel_launch(void* const* d_in, const int* in_sizes, int n_in,
                              void* d_out, int out_size, void* d_ws, size_t ws_size,
                              hipStream_t stream)
{
    const float* fmaps = (const float*)d_in[0];
    const int*   sel   = (const int*)  d_in[1];
    const float* mean  = (const float*)d_in[2];
    const float* cov   = (const float*)d_in[3];
    const float* minp  = (const float*)d_in[4];
    const float* maxp  = (const float*)d_in[5];
    float* out = (float*)d_out;

    half4* xbuf  = (half4*)d_ws;                                  // NN*CC*HW fp16 (5.0 MB)
    float* qpart = (float*)((char*)d_ws + (size_t)NN*CC*HW*2);    // NPAIR*NN*HW f32 (5.0 MB)
    float* smap  = qpart + (size_t)NPAIR * NN * HW;               // NN*HW f32 (0.1 MB)

    {
        const int total = NN * CC * NPIX4;
        prep_x_kernel<<<(total + 255) / 256, 256, 0, stream>>>(fmaps, sel, mean, xbuf);
    }
    qform_kernel<<<NT4 * NPAIR, 512, 0, stream>>>(xbuf, cov, qpart);
    {
        const int total = NN * NPIX4;
        reduce_kernel<<<(total + 255) / 256, 256, 0, stream>>>(qpart, smap);
    }
    {
        const int total = NN * OH * OW;
        upsample_kernel<<<(total + 255) / 256, 256, 0, stream>>>(smap, minp, maxp, out);
    }
}